// Round 1
// baseline (1779.341 us; speedup 1.0000x reference)
//
#include <hip/hip_runtime.h>
#include <stdint.h>

// Problem constants (match reference)
#define B_    1024
#define FV_   4096
#define E_    256
#define Z_    257
#define NS_   16
#define NSB_  16384   // NS*B
#define EPS_  1e-3f

// ---------------- threefry2x32 (JAX-compatible, 20 rounds) ----------------
__host__ __device__ __forceinline__ uint32_t rotl32(uint32_t v, int r){
  return (v << r) | (v >> (32 - r));
}

__host__ __device__ __forceinline__ void tf2x32(uint32_t k0, uint32_t k1,
    uint32_t x0, uint32_t x1, uint32_t* o0, uint32_t* o1){
  uint32_t ks2 = k0 ^ k1 ^ 0x1BD11BDAu;
  x0 += k0; x1 += k1;
#define TFR(r) { x0 += x1; x1 = rotl32(x1, (r)); x1 ^= x0; }
  TFR(13) TFR(15) TFR(26) TFR(6)
  x0 += k1;  x1 += ks2 + 1u;
  TFR(17) TFR(29) TFR(16) TFR(24)
  x0 += ks2; x1 += k0 + 2u;
  TFR(13) TFR(15) TFR(26) TFR(6)
  x0 += k0;  x1 += k1 + 3u;
  TFR(17) TFR(29) TFR(16) TFR(24)
  x0 += k1;  x1 += ks2 + 4u;
  TFR(13) TFR(15) TFR(26) TFR(6)
  x0 += ks2; x1 += k0 + 5u;
#undef TFR
  *o0 = x0; *o1 = x1;
}

// partitionable-mode random bits for element index i: xor-fold of tf(key,(0,i))
__device__ __forceinline__ uint32_t tf_fold(uint32_t k0, uint32_t k1, uint32_t i){
  uint32_t a, b; tf2x32(k0, k1, 0u, i, &a, &b); return a ^ b;
}
__device__ __forceinline__ float u01(uint32_t bits){
  return __uint_as_float((bits >> 9) | 0x3f800000u) - 1.0f;
}
__device__ __forceinline__ float logsigf(float x){
  return fminf(x, 0.f) - log1pf(expf(-fabsf(x)));
}
__device__ __forceinline__ float sigf(float x){ return 1.f / (1.f + expf(-x)); }

// ---------------- small setup kernels ----------------
__global__ void k_fill(float* p, int n, float v){
  int i = blockIdx.x * 256 + threadIdx.x;
  if (i < n) p[i] = v;
}

__global__ void k_transpose(const float* __restrict__ whz, float* __restrict__ whzT){
  int z = blockIdx.x;           // 0..256
  int e = threadIdx.x;          // 0..255
  whzT[(size_t)z * E_ + e] = whz[(size_t)e * Z_ + z];
}

__global__ void k_r2(const float* __restrict__ img, const float* __restrict__ wb,
                     float* __restrict__ r2){
  int b = blockIdx.x, t = threadIdx.x;
  float s = 0.f;
  for (int f = t; f < FV_; f += 256){
    float v = img[(size_t)b * FV_ + f] - wb[f];
    s = fmaf(v, v, s);
  }
  __shared__ float red[256];
  red[t] = s; __syncthreads();
  for (int w = 128; w > 0; w >>= 1){ if (t < w) red[t] += red[t + w]; __syncthreads(); }
  if (!t) r2[b] = red[0];
}

// G = W^T W   (E x E, K = FV), tiles 64x64x16
__global__ __launch_bounds__(256) void k_ata(const float* __restrict__ W, float* __restrict__ G){
  __shared__ float As[16][68], Bs[16][68];
  int tid = threadIdx.x, tx = tid & 15, ty = tid >> 4;
  int i0 = blockIdx.y << 6, j0 = blockIdx.x << 6;
  float acc[4][4] = {};
  for (int f0 = 0; f0 < FV_; f0 += 16){
#pragma unroll
    for (int q = 0; q < 4; q++){
      int idx = tid + (q << 8);
      int c = idx & 63, kk = idx >> 6;
      As[kk][c] = W[(size_t)(f0 + kk) * E_ + i0 + c];
      Bs[kk][c] = W[(size_t)(f0 + kk) * E_ + j0 + c];
    }
    __syncthreads();
#pragma unroll
    for (int kk = 0; kk < 16; kk++){
      float4 av = *(const float4*)&As[kk][ty << 2];
      float4 bv = *(const float4*)&Bs[kk][tx << 2];
      float a[4] = {av.x, av.y, av.z, av.w}, b[4] = {bv.x, bv.y, bv.z, bv.w};
#pragma unroll
      for (int i = 0; i < 4; i++)
#pragma unroll
        for (int j = 0; j < 4; j++) acc[i][j] = fmaf(a[i], b[j], acc[i][j]);
    }
    __syncthreads();
  }
#pragma unroll
  for (int i = 0; i < 4; i++)
#pragma unroll
    for (int j = 0; j < 4; j++)
      G[(size_t)(i0 + (ty << 2) + i) * E_ + j0 + (tx << 2) + j] = acc[i][j];
}

// Pp = (img - wb) @ W   (B x E, K = FV), NN layout
__global__ __launch_bounds__(256) void k_pp(const float* __restrict__ img,
    const float* __restrict__ wb, const float* __restrict__ W, float* __restrict__ Pp){
  __shared__ float As[16][68], Bs[16][68];
  int tid = threadIdx.x, tx = tid & 15, ty = tid >> 4;
  int m0 = blockIdx.y << 6, n0 = blockIdx.x << 6;
  float acc[4][4] = {};
  for (int kt = 0; kt < FV_; kt += 16){
#pragma unroll
    for (int q = 0; q < 4; q++){
      int idx = tid + (q << 8);
      { int r = idx >> 4, kk = idx & 15;
        As[kk][r] = img[(size_t)(m0 + r) * FV_ + kt + kk] - wb[kt + kk]; }
      { int n = idx & 63, kk = idx >> 6;
        Bs[kk][n] = W[(size_t)(kt + kk) * E_ + n0 + n]; }
    }
    __syncthreads();
#pragma unroll
    for (int kk = 0; kk < 16; kk++){
      float4 av = *(const float4*)&As[kk][ty << 2];
      float4 bv = *(const float4*)&Bs[kk][tx << 2];
      float a[4] = {av.x, av.y, av.z, av.w}, b[4] = {bv.x, bv.y, bv.z, bv.w};
#pragma unroll
      for (int i = 0; i < 4; i++)
#pragma unroll
        for (int j = 0; j < 4; j++) acc[i][j] = fmaf(a[i], b[j], acc[i][j]);
    }
    __syncthreads();
  }
#pragma unroll
  for (int i = 0; i < 4; i++)
#pragma unroll
    for (int j = 0; j < 4; j++)
      Pp[(size_t)(m0 + (ty << 2) + i) * E_ + n0 + (tx << 2) + j] = acc[i][j];
}

// ---------------- generic NT GEMM with fused epilogues ----------------
// C[M,N] = A[M,K](lda) * B[N,K](ldb)^T ; A optionally u8.
struct GP {
  const float* A; const float* Bm; float* C;
  int M, N, K, lda, ldb;
  const float* bias;     // whz_b
  const float* Pp;       // [B,E]
  const float* aux;      // dh2 (mode 2 input)
  float* w0; float* w1;  // mode 1 outputs (dh2, sigr)
  const float* oldv; float* newv;
  const float* blp; const float* bso;
  uint32_t k0, k1;
};

template<int MODE, bool A8>
__global__ __launch_bounds__(256) void gemm_nt(GP p){
  __shared__ float As[16][68], Bs[16][68];
  const int tid = threadIdx.x, tx = tid & 15, ty = tid >> 4;
  const int m0 = blockIdx.y << 6, n0 = blockIdx.x << 6;
  const unsigned char* A8p = (const unsigned char*)p.A;
  float acc[4][4] = {};
  for (int kt = 0; kt < p.K; kt += 16){
#pragma unroll
    for (int q = 0; q < 4; q++){
      int idx = tid + (q << 8);
      int r = idx >> 4, kk = idx & 15;
      int k = kt + kk;
      int ma = m0 + r, nb = n0 + r;
      float av = 0.f;
      if (ma < p.M && k < p.K)
        av = A8 ? (float)A8p[(size_t)ma * p.lda + k] : p.A[(size_t)ma * p.lda + k];
      As[kk][r] = av;
      Bs[kk][r] = (nb < p.N && k < p.K) ? p.Bm[(size_t)nb * p.ldb + k] : 0.f;
    }
    __syncthreads();
#pragma unroll
    for (int kk = 0; kk < 16; kk++){
      float4 av = *(const float4*)&As[kk][ty << 2];
      float4 bv = *(const float4*)&Bs[kk][tx << 2];
      float a[4] = {av.x, av.y, av.z, av.w}, b[4] = {bv.x, bv.y, bv.z, bv.w};
#pragma unroll
      for (int i = 0; i < 4; i++)
#pragma unroll
        for (int j = 0; j < 4; j++) acc[i][j] = fmaf(a[i], b[j], acc[i][j]);
    }
    __syncthreads();
  }
#pragma unroll
  for (int i = 0; i < 4; i++){
    int m = m0 + (ty << 2) + i;
    if (m >= p.M) continue;
#pragma unroll
    for (int j = 0; j < 4; j++){
      int n = n0 + (tx << 2) + j;
      if (n >= p.N) continue;
      float a = acc[i][j];
      if constexpr (MODE == 0){                 // plain store (v = h @ G)
        p.C[(size_t)m * p.N + n] = a;
      } else if constexpr (MODE == 1){          // hpl -> dh2, sigr
        float hpl = a + p.bias[n];
        size_t fl = (size_t)m * E_ + n;
        p.w0[fl] = logsigf(hpl);                        // dh2 = log_sigmoid(hpl)
        p.w1[fl] = p.oldv[fl] * (1.f / (1.f + expf(hpl))); // node_h * sigmoid(-hpl)
      } else if constexpr (MODE == 2){          // node_h update
        float op = expf(2.f * p.bso[0]);
        size_t fl = (size_t)m * E_ + n;
        float dh1 = op * (p.Pp[fl] - a);
        float hn = sigf(dh1 + p.aux[fl]);
        uint32_t bits = tf_fold(p.k0, p.k1, (uint32_t)fl);
        float old = p.oldv[fl];
        p.newv[fl] = (bits < 0x80000000u) ? 0.5f * (old + hn) : old;  // u < 0.5
      } else if constexpr (MODE == 3){          // node_z update
        size_t fl = (size_t)m * Z_ + n;
        float dz1 = a + logsigf(p.blp[n]);
        float zx = sigf(dz1);
        uint32_t bits = tf_fold(p.k0, p.k1, (uint32_t)fl);
        float old = p.oldv[fl];
        p.newv[fl] = (bits < 0x80000000u) ? 0.5f * (old + zx) : old;
      } else {                                   // MODE 4: h_noise sample (u8)
        size_t fl = (size_t)m * E_ + n;
        float pr = sigf(a + p.bias[n]);
        float u = u01(tf_fold(p.k0, p.k1, (uint32_t)fl));
        ((unsigned char*)p.C)[fl] = (u < pr) ? 1 : 0;
      }
    }
  }
}

// ---------------- phase-2 kernels ----------------
// z_noise sample (u8) + lp_internal reduction per (n,b)
__global__ __launch_bounds__(256) void k_znoise(const float* __restrict__ nz,
    const float* __restrict__ blp, unsigned char* __restrict__ zn,
    float* __restrict__ lpint, uint32_t k0, uint32_t k1){
  int blk = blockIdx.x;            // n*B + b, 16384 blocks
  int b = blk & (B_ - 1);
  int t = threadIdx.x;
  float s = 0.f;
  for (int z = t; z < Z_; z += 256){
    float pz = nz[(size_t)b * Z_ + z];
    uint32_t i = (uint32_t)blk * (uint32_t)Z_ + (uint32_t)z;
    float u = u01(tf_fold(k0, k1, i));
    float zv = (u < pz) ? 1.f : 0.f;
    zn[(size_t)blk * Z_ + z] = (unsigned char)zv;
    float x = blp[z];
    float sp = fmaxf(x, 0.f) + log1pf(expf(-fabsf(x)));         // softplus
    float post = zv * logf(pz) + (1.f - zv) * log1pf(-pz);
    s += zv * x - sp - post;
  }
  __shared__ float red[256];
  red[t] = s; __syncthreads();
  for (int w = 128; w > 0; w >>= 1){ if (t < w) red[t] += red[t + w]; __syncthreads(); }
  if (!t) lpint[blk] = red[0];
}

// joint[m] = lp_int[m] - 0.5*exp(-2*bso)*(r2[b] - 2*h.Pp[b] + h.v) - FV*(bso + 0.5*log(2pi))
__global__ __launch_bounds__(256) void k_joint(const unsigned char* __restrict__ hN,
    const float* __restrict__ v, const float* __restrict__ Pp,
    const float* __restrict__ r2, const float* __restrict__ lpint,
    const float* __restrict__ bso, float* __restrict__ joint){
  int m = blockIdx.x, t = threadIdx.x;
  int b = m & (B_ - 1);
  float h = (float)hN[(size_t)m * E_ + t];
  float s1 = h * v[(size_t)m * E_ + t];
  float s2 = h * Pp[(size_t)b * E_ + t];
  __shared__ float rA[256], rB[256];
  rA[t] = s1; rB[t] = s2; __syncthreads();
  for (int w = 128; w > 0; w >>= 1){
    if (t < w){ rA[t] += rA[t + w]; rB[t] += rB[t + w]; }
    __syncthreads();
  }
  if (!t){
    float bs = bso[0];
    float isc2 = expf(-2.f * bs);
    float se = r2[b] - 2.f * rB[0] + rA[0];
    joint[m] = lpint[m] - 0.5f * isc2 * se - (float)FV_ * (bs + 0.91893853320467274f);
  }
}

// lse over NS, mean over B, negate
__global__ __launch_bounds__(1024) void k_final(const float* __restrict__ joint, float* __restrict__ out){
  int b = threadIdx.x;   // 1024
  float mx = -3.0e38f;
  for (int n = 0; n < NS_; n++) mx = fmaxf(mx, joint[(size_t)n * B_ + b]);
  float s = 0.f;
  for (int n = 0; n < NS_; n++) s += expf(joint[(size_t)n * B_ + b] - mx);
  float lse = mx + logf(s) - logf((float)NS_);
  __shared__ float red[1024];
  red[b] = lse; __syncthreads();
  for (int w = 512; w > 0; w >>= 1){ if (b < w) red[b] += red[b + w]; __syncthreads(); }
  if (!b) out[0] = -red[0] / (float)B_;
}

// ---------------- host ----------------
extern "C" void kernel_launch(void* const* d_in, const int* in_sizes, int n_in,
                              void* d_out, int out_size, void* d_ws, size_t ws_size,
                              hipStream_t stream){
  const float* img  = (const float*)d_in[0];
  // d_in[1] = lab (unused)
  const float* W    = (const float*)d_in[2];   // [FV,E]
  const float* wb   = (const float*)d_in[3];   // [FV]
  const float* whz  = (const float*)d_in[4];   // [E,Z]
  const float* whzb = (const float*)d_in[5];   // [E]
  const float* blp  = (const float*)d_in[6];   // [Z]
  const float* bso  = (const float*)d_in[7];   // scalar
  float* out = (float*)d_out;
  float* ws = (float*)d_ws;

  // workspace layout (floats), ~33 MB total
  size_t off = 0;
  auto nxt = [&](size_t n){ size_t o = off; off += (n + 63) & ~(size_t)63; return o; };
  float* G     = ws + nxt((size_t)E_ * E_);
  float* Pp    = ws + nxt((size_t)B_ * E_);
  float* r2    = ws + nxt(B_);
  float* whzT  = ws + nxt((size_t)Z_ * E_);
  float* nhA   = ws + nxt((size_t)B_ * E_);
  float* nhB   = ws + nxt((size_t)B_ * E_);
  float* nzA   = ws + nxt((size_t)B_ * Z_);
  float* nzB   = ws + nxt((size_t)B_ * Z_);
  float* dh2   = ws + nxt((size_t)B_ * E_);
  float* sigr  = ws + nxt((size_t)B_ * E_);
  float* lpint = ws + nxt(NSB_);
  float* joint = ws + nxt(NSB_);
  unsigned char* zn = (unsigned char*)(ws + nxt(((size_t)NSB_ * Z_ + 3) / 4));
  unsigned char* hN = (unsigned char*)(ws + nxt(((size_t)NSB_ * E_ + 3) / 4));
  float* v     = ws + nxt((size_t)NSB_ * E_);
  (void)ws_size; (void)in_sizes; (void)n_in; (void)out_size;

  // ---- host-side threefry key derivation (partitionable / foldlike split) ----
  uint32_t lk0[8], lk1[8];
  for (uint32_t s = 0; s < 8; s++) tf2x32(0u, 42u, 0u, s, &lk0[s], &lk1[s]);
  uint32_t k1s0[8], k1s1[8], k2s0[8], k2s1[8];
  for (int s = 0; s < 8; s++){
    tf2x32(lk0[s], lk1[s], 0u, 0u, &k1s0[s], &k1s1[s]);  // k1 = split(k)[0]
    tf2x32(lk0[s], lk1[s], 0u, 1u, &k2s0[s], &k2s1[s]);  // k2 = split(k)[1]
  }
  uint32_t sk00, sk01, sk10, sk11;
  tf2x32(0u, 7u, 0u, 0u, &sk00, &sk01);   // sk[0] -> z_noise
  tf2x32(0u, 7u, 0u, 1u, &sk10, &sk11);   // sk[1] -> h_noise

  // ---- setup ----
  k_transpose<<<dim3(Z_), dim3(E_), 0, stream>>>(whz, whzT);
  k_ata<<<dim3(4, 4), dim3(256), 0, stream>>>(W, G);
  k_pp<<<dim3(4, 16), dim3(256), 0, stream>>>(img, wb, W, Pp);
  k_r2<<<dim3(B_), dim3(256), 0, stream>>>(img, wb, r2);
  k_fill<<<dim3((B_ * E_ + 255) / 256), dim3(256), 0, stream>>>(nhA, B_ * E_, EPS_);
  k_fill<<<dim3((B_ * Z_ + 255) / 256), dim3(256), 0, stream>>>(nzA, B_ * Z_, EPS_);

  float* nh_c = nhA; float* nh_n = nhB;
  float* nz_c = nzA; float* nz_n = nzB;

  for (int s = 0; s < 8; s++){
    // (a) hpl = nz @ whz^T + whzb -> dh2, sigr
    GP p1 = {};
    p1.A = nz_c; p1.Bm = whz; p1.M = B_; p1.N = E_; p1.K = Z_; p1.lda = Z_; p1.ldb = Z_;
    p1.bias = whzb; p1.oldv = nh_c; p1.w0 = dh2; p1.w1 = sigr;
    gemm_nt<1, false><<<dim3(4, 16), 256, 0, stream>>>(p1);
    // (b) acc = nh @ G ; node_h update
    GP p2 = {};
    p2.A = nh_c; p2.Bm = G; p2.M = B_; p2.N = E_; p2.K = E_; p2.lda = E_; p2.ldb = E_;
    p2.Pp = Pp; p2.aux = dh2; p2.oldv = nh_c; p2.newv = nh_n; p2.bso = bso;
    p2.k0 = k1s0[s]; p2.k1 = k1s1[s];
    gemm_nt<2, false><<<dim3(4, 16), 256, 0, stream>>>(p2);
    // (c) dz1 = sigr @ whz + log_sigmoid(blp) ; node_z update
    GP p3 = {};
    p3.A = sigr; p3.Bm = whzT; p3.M = B_; p3.N = Z_; p3.K = E_; p3.lda = E_; p3.ldb = E_;
    p3.blp = blp; p3.oldv = nz_c; p3.newv = nz_n;
    p3.k0 = k2s0[s]; p3.k1 = k2s1[s];
    gemm_nt<3, false><<<dim3(5, 16), 256, 0, stream>>>(p3);
    { float* t = nh_c; nh_c = nh_n; nh_n = t; }
    { float* t = nz_c; nz_c = nz_n; nz_n = t; }
  }

  // ---- phase 2 ----
  k_znoise<<<dim3(NSB_), dim3(256), 0, stream>>>(nz_c, blp, zn, lpint, sk00, sk01);

  GP p4 = {};   // hpl2 = zn @ whz^T + whzb ; h_noise sample
  p4.A = (const float*)zn; p4.Bm = whz; p4.C = (float*)hN;
  p4.M = NSB_; p4.N = E_; p4.K = Z_; p4.lda = Z_; p4.ldb = Z_;
  p4.bias = whzb; p4.k0 = sk10; p4.k1 = sk11;
  gemm_nt<4, true><<<dim3(4, 256), 256, 0, stream>>>(p4);

  GP p0 = {};   // v = h @ G
  p0.A = (const float*)hN; p0.Bm = G; p0.C = v;
  p0.M = NSB_; p0.N = E_; p0.K = E_; p0.lda = E_; p0.ldb = E_;
  gemm_nt<0, true><<<dim3(4, 256), 256, 0, stream>>>(p0);

  k_joint<<<dim3(NSB_), dim3(256), 0, stream>>>(hN, v, Pp, r2, lpint, bso, joint);
  k_final<<<dim3(1), dim3(1024), 0, stream>>>(joint, out);
}

// Round 2
// 506.608 us; speedup vs baseline: 3.5123x; 3.5123x over previous
//
#include <hip/hip_runtime.h>
#include <stdint.h>

// Problem constants
#define B_    1024
#define FV_   4096
#define E_    256
#define Z_    257
#define NS_   16
#define NSB_  16384
#define EPS_  1e-3f

// ---------------- threefry2x32 (JAX-compatible, 20 rounds) ----------------
__host__ __device__ __forceinline__ uint32_t rotl32(uint32_t v, int r){
  return (v << r) | (v >> (32 - r));
}
__host__ __device__ __forceinline__ void tf2x32(uint32_t k0, uint32_t k1,
    uint32_t x0, uint32_t x1, uint32_t* o0, uint32_t* o1){
  uint32_t ks2 = k0 ^ k1 ^ 0x1BD11BDAu;
  x0 += k0; x1 += k1;
#define TFR(r) { x0 += x1; x1 = rotl32(x1, (r)); x1 ^= x0; }
  TFR(13) TFR(15) TFR(26) TFR(6)
  x0 += k1;  x1 += ks2 + 1u;
  TFR(17) TFR(29) TFR(16) TFR(24)
  x0 += ks2; x1 += k0 + 2u;
  TFR(13) TFR(15) TFR(26) TFR(6)
  x0 += k0;  x1 += k1 + 3u;
  TFR(17) TFR(29) TFR(16) TFR(24)
  x0 += k1;  x1 += ks2 + 4u;
  TFR(13) TFR(15) TFR(26) TFR(6)
  x0 += ks2; x1 += k0 + 5u;
#undef TFR
  *o0 = x0; *o1 = x1;
}
__device__ __forceinline__ uint32_t tf_fold(uint32_t k0, uint32_t k1, uint32_t i){
  uint32_t a, b; tf2x32(k0, k1, 0u, i, &a, &b); return a ^ b;
}
__device__ __forceinline__ float u01(uint32_t bits){
  return __uint_as_float((bits >> 9) | 0x3f800000u) - 1.0f;
}
__device__ __forceinline__ float logsigf(float x){
  return fminf(x, 0.f) - log1pf(__expf(-fabsf(x)));
}
__device__ __forceinline__ float sigf(float x){ return 1.f / (1.f + __expf(-x)); }

// bf16 helpers
__device__ __forceinline__ unsigned short f2bf(float f){
  uint32_t b = __float_as_uint(f);
  return (unsigned short)((b + 0x7fffu + ((b >> 16) & 1u)) >> 16);
}
__device__ __forceinline__ float bf2f(unsigned short u){
  return __uint_as_float(((uint32_t)u) << 16);
}
__device__ __forceinline__ float4 bf4(ushort4 u){
  return make_float4(bf2f(u.x), bf2f(u.y), bf2f(u.z), bf2f(u.w));
}
__device__ __forceinline__ float dot4(float4 a, float4 b, float acc){
  return fmaf(a.x, b.x, fmaf(a.y, b.y, fmaf(a.z, b.z, fmaf(a.w, b.w, acc))));
}

// ---------------- prep: padded bf16 weight copies ----------------
// whzPh [256][260] (row e of whz, zero-padded), whzTPh [257][256] (transpose)
__global__ void k_prep(const float* __restrict__ whz,
                       unsigned short* __restrict__ whzPh,
                       unsigned short* __restrict__ whzTPh){
  int bz = blockIdx.x, t = threadIdx.x;     // grid 257 x 256
  whzTPh[(size_t)bz * E_ + t] = f2bf(whz[(size_t)t * Z_ + bz]);
  if (bz < E_){
    for (int z = t; z < 260; z += 256)
      whzPh[(size_t)bz * 260 + z] = (z < Z_) ? f2bf(whz[(size_t)bz * Z_ + z]) : (unsigned short)0;
  }
}

__global__ void k_r2(const float* __restrict__ img, const float* __restrict__ wb,
                     float* __restrict__ r2){
  int b = blockIdx.x, t = threadIdx.x;
  float s = 0.f;
  for (int f = t; f < FV_; f += 256){
    float v = img[(size_t)b * FV_ + f] - wb[f];
    s = fmaf(v, v, s);
  }
  __shared__ float red[256];
  red[t] = s; __syncthreads();
  for (int w = 128; w > 0; w >>= 1){ if (t < w) red[t] += red[t + w]; __syncthreads(); }
  if (!t) r2[b] = red[0];
}

// G = W^T W, split-K: grid (4,4,16), K-chunk 256
__global__ __launch_bounds__(256) void k_ata_split(const float* __restrict__ W,
                                                   float* __restrict__ part){
  __shared__ float As[16][68], Bs[16][68];
  int tid = threadIdx.x, tx = tid & 15, ty = tid >> 4;
  int i0 = blockIdx.y << 6, j0 = blockIdx.x << 6;
  int f0 = blockIdx.z << 8;
  float acc[4][4] = {};
  for (int fk = f0; fk < f0 + 256; fk += 16){
#pragma unroll
    for (int q = 0; q < 4; q++){
      int idx = tid + (q << 8);
      int c = idx & 63, kk = idx >> 6;
      As[kk][c] = W[(size_t)(fk + kk) * E_ + i0 + c];
      Bs[kk][c] = W[(size_t)(fk + kk) * E_ + j0 + c];
    }
    __syncthreads();
#pragma unroll
    for (int kk = 0; kk < 16; kk++){
      float4 av = *(const float4*)&As[kk][ty << 2];
      float4 bv = *(const float4*)&Bs[kk][tx << 2];
      float a[4] = {av.x, av.y, av.z, av.w}, b[4] = {bv.x, bv.y, bv.z, bv.w};
#pragma unroll
      for (int i = 0; i < 4; i++)
#pragma unroll
        for (int j = 0; j < 4; j++) acc[i][j] = fmaf(a[i], b[j], acc[i][j]);
    }
    __syncthreads();
  }
  float* dst = part + (size_t)blockIdx.z * E_ * E_;
#pragma unroll
  for (int i = 0; i < 4; i++)
#pragma unroll
    for (int j = 0; j < 4; j++)
      dst[(size_t)(i0 + (ty << 2) + i) * E_ + j0 + (tx << 2) + j] = acc[i][j];
}

// Pp = (img - wb) @ W, split-K: grid (4,16,16), K-chunk 256
__global__ __launch_bounds__(256) void k_pp_split(const float* __restrict__ img,
    const float* __restrict__ wb, const float* __restrict__ W, float* __restrict__ part){
  __shared__ float As[16][68], Bs[16][68];
  int tid = threadIdx.x, tx = tid & 15, ty = tid >> 4;
  int m0 = blockIdx.y << 6, n0 = blockIdx.x << 6;
  int k0 = blockIdx.z << 8;
  float acc[4][4] = {};
  for (int kt = k0; kt < k0 + 256; kt += 16){
#pragma unroll
    for (int q = 0; q < 4; q++){
      int idx = tid + (q << 8);
      { int r = idx >> 4, kk = idx & 15;
        As[kk][r] = img[(size_t)(m0 + r) * FV_ + kt + kk] - wb[kt + kk]; }
      { int n = idx & 63, kk = idx >> 6;
        Bs[kk][n] = W[(size_t)(kt + kk) * E_ + n0 + n]; }
    }
    __syncthreads();
#pragma unroll
    for (int kk = 0; kk < 16; kk++){
      float4 av = *(const float4*)&As[kk][ty << 2];
      float4 bv = *(const float4*)&Bs[kk][tx << 2];
      float a[4] = {av.x, av.y, av.z, av.w}, b[4] = {bv.x, bv.y, bv.z, bv.w};
#pragma unroll
      for (int i = 0; i < 4; i++)
#pragma unroll
        for (int j = 0; j < 4; j++) acc[i][j] = fmaf(a[i], b[j], acc[i][j]);
    }
    __syncthreads();
  }
  float* dst = part + (size_t)blockIdx.z * B_ * E_;
#pragma unroll
  for (int i = 0; i < 4; i++)
#pragma unroll
    for (int j = 0; j < 4; j++)
      dst[(size_t)(m0 + (ty << 2) + i) * E_ + n0 + (tx << 2) + j] = acc[i][j];
}

// sum 16 partials; optional bf16 second output
__global__ void k_reduce16(const float* __restrict__ src, float* __restrict__ dstF,
                           unsigned short* __restrict__ dstH, int n){
  int i = blockIdx.x * 256 + threadIdx.x;
  if (i >= n) return;
  float s = 0.f;
#pragma unroll
  for (int p = 0; p < 16; p++) s += src[(size_t)p * n + i];
  dstF[i] = s;
  if (dstH) dstH[i] = f2bf(s);
}

// ---------------- fused 8-step inner loop ----------------
// 256 blocks x 512 threads; 4 rows per block; h/z state lives in LDS.
__global__ __launch_bounds__(512) void k_inner(
    const unsigned short* __restrict__ whzPh,   // [256][260] bf16
    const unsigned short* __restrict__ whzTPh,  // [257][256] bf16
    const unsigned short* __restrict__ Gh,      // [256][256] bf16
    const float* __restrict__ whzb,
    const float* __restrict__ blp,
    const float* __restrict__ Pp,               // [B][E]
    const float* __restrict__ bso,
    float* __restrict__ nzOut)                  // [B][Z]
{
  __shared__ float zl[4][260];
  __shared__ float hl[4][256];
  __shared__ float sg[4][256];
  __shared__ float d2[4][256];
  __shared__ float lsb[257];
  __shared__ uint32_t klds[8][4];

  const int t = threadIdx.x;
  const int e = t & 255;
  const int rp = t >> 8;
  const int r0 = rp * 2, r1 = rp * 2 + 1;
  const int b0 = blockIdx.x * 4;

  for (int i = t; i < 4 * 260; i += 512) zl[i / 260][i % 260] = (i % 260) < Z_ ? EPS_ : 0.f;
  for (int i = t; i < 4 * 256; i += 512) hl[i >> 8][i & 255] = EPS_;
  if (t < Z_) lsb[t] = logsigf(blp[t]);
  if (t < 8){
    uint32_t l0, l1, a, b, c, d;
    tf2x32(0u, 42u, 0u, (uint32_t)t, &l0, &l1);
    tf2x32(l0, l1, 0u, 0u, &a, &b);   // k1 (h-select)
    tf2x32(l0, l1, 0u, 1u, &c, &d);   // k2 (z-select)
    klds[t][0] = a; klds[t][1] = b; klds[t][2] = c; klds[t][3] = d;
  }
  __syncthreads();

  const float wbv = whzb[e];
  const float op = __expf(2.f * bso[0]);
  const float pp0 = Pp[(size_t)(b0 + r0) * E_ + e];
  const float pp1 = Pp[(size_t)(b0 + r1) * E_ + e];
  const ushort4* wP  = (const ushort4*)(whzPh  + (size_t)e * 260);
  const ushort4* wG  = (const ushort4*)(Gh     + (size_t)e * 256);
  const ushort4* wT  = (const ushort4*)(whzTPh + (size_t)e * 256);
  const ushort4* wT2 = (const ushort4*)(whzTPh + (size_t)256 * 256);

  for (int s = 0; s < 8; s++){
    // ---- A: hpl = z @ whz^T + b ----
    float a0 = 0.f, a1 = 0.f;
    for (int q = 0; q < 65; q++){
      float4 w  = bf4(wP[q]);
      float4 x0 = *(const float4*)&zl[r0][q << 2];
      float4 x1 = *(const float4*)&zl[r1][q << 2];
      a0 = dot4(w, x0, a0);
      a1 = dot4(w, x1, a1);
    }
    float hpl0 = a0 + wbv, hpl1 = a1 + wbv;
    d2[r0][e] = logsigf(hpl0);
    d2[r1][e] = logsigf(hpl1);
    sg[r0][e] = hl[r0][e] * (1.f / (1.f + __expf(hpl0)));
    sg[r1][e] = hl[r1][e] * (1.f / (1.f + __expf(hpl1)));
    __syncthreads();

    // ---- B: gh = h @ G (G symmetric) and dz = sigr @ whz ----
    float g0 = 0.f, g1 = 0.f, q0 = 0.f, q1 = 0.f;
    for (int q = 0; q < 64; q++){
      float4 gw = bf4(wG[q]);
      float4 h0 = *(const float4*)&hl[r0][q << 2];
      float4 h1 = *(const float4*)&hl[r1][q << 2];
      g0 = dot4(gw, h0, g0);
      g1 = dot4(gw, h1, g1);
      float4 tw = bf4(wT[q]);
      float4 s0 = *(const float4*)&sg[r0][q << 2];
      float4 s1 = *(const float4*)&sg[r1][q << 2];
      q0 = dot4(tw, s0, q0);
      q1 = dot4(tw, s1, q1);
    }
    float qe0 = 0.f, qe1 = 0.f;
    if (e == 0){
      for (int q = 0; q < 64; q++){
        float4 tw = bf4(wT2[q]);
        float4 s0 = *(const float4*)&sg[r0][q << 2];
        float4 s1 = *(const float4*)&sg[r1][q << 2];
        qe0 = dot4(tw, s0, qe0);
        qe1 = dot4(tw, s1, qe1);
      }
    }
    __syncthreads();

    // ---- C: stochastic mixing updates ----
    const uint32_t hk0 = klds[s][0], hk1 = klds[s][1];
    const uint32_t zk0 = klds[s][2], zk1 = klds[s][3];
    {
      float hn0 = sigf(op * (pp0 - g0) + d2[r0][e]);
      if (tf_fold(hk0, hk1, (uint32_t)((b0 + r0) * E_ + e)) < 0x80000000u)
        hl[r0][e] = 0.5f * (hl[r0][e] + hn0);
      float hn1 = sigf(op * (pp1 - g1) + d2[r1][e]);
      if (tf_fold(hk0, hk1, (uint32_t)((b0 + r1) * E_ + e)) < 0x80000000u)
        hl[r1][e] = 0.5f * (hl[r1][e] + hn1);
    }
    {
      float zx0 = sigf(q0 + lsb[e]);
      if (tf_fold(zk0, zk1, (uint32_t)((b0 + r0) * Z_ + e)) < 0x80000000u)
        zl[r0][e] = 0.5f * (zl[r0][e] + zx0);
      float zx1 = sigf(q1 + lsb[e]);
      if (tf_fold(zk0, zk1, (uint32_t)((b0 + r1) * Z_ + e)) < 0x80000000u)
        zl[r1][e] = 0.5f * (zl[r1][e] + zx1);
      if (e == 0){
        float ze0 = sigf(qe0 + lsb[256]);
        if (tf_fold(zk0, zk1, (uint32_t)((b0 + r0) * Z_ + 256)) < 0x80000000u)
          zl[r0][256] = 0.5f * (zl[r0][256] + ze0);
        float ze1 = sigf(qe1 + lsb[256]);
        if (tf_fold(zk0, zk1, (uint32_t)((b0 + r1) * Z_ + 256)) < 0x80000000u)
          zl[r1][256] = 0.5f * (zl[r1][256] + ze1);
      }
    }
    __syncthreads();
  }

  nzOut[(size_t)(b0 + r0) * Z_ + e] = zl[r0][e];
  nzOut[(size_t)(b0 + r1) * Z_ + e] = zl[r1][e];
  if (e == 0){
    nzOut[(size_t)(b0 + r0) * Z_ + 256] = zl[r0][256];
    nzOut[(size_t)(b0 + r1) * Z_ + 256] = zl[r1][256];
  }
}

// ---------------- generic NT GEMM (phase-2 only) ----------------
struct GP {
  const float* A; const float* Bm; float* C;
  int M, N, K, lda, ldb;
  const float* bias;
  uint32_t k0, k1;
};

template<int MODE, bool A8>
__global__ __launch_bounds__(256) void gemm_nt(GP p){
  __shared__ float As[16][68], Bs[16][68];
  const int tid = threadIdx.x, tx = tid & 15, ty = tid >> 4;
  const int m0 = blockIdx.y << 6, n0 = blockIdx.x << 6;
  const unsigned char* A8p = (const unsigned char*)p.A;
  float acc[4][4] = {};
  for (int kt = 0; kt < p.K; kt += 16){
#pragma unroll
    for (int q = 0; q < 4; q++){
      int idx = tid + (q << 8);
      int r = idx >> 4, kk = idx & 15;
      int k = kt + kk;
      int ma = m0 + r, nb = n0 + r;
      float av = 0.f;
      if (ma < p.M && k < p.K)
        av = A8 ? (float)A8p[(size_t)ma * p.lda + k] : p.A[(size_t)ma * p.lda + k];
      As[kk][r] = av;
      Bs[kk][r] = (nb < p.N && k < p.K) ? p.Bm[(size_t)nb * p.ldb + k] : 0.f;
    }
    __syncthreads();
#pragma unroll
    for (int kk = 0; kk < 16; kk++){
      float4 av = *(const float4*)&As[kk][ty << 2];
      float4 bv = *(const float4*)&Bs[kk][tx << 2];
      float a[4] = {av.x, av.y, av.z, av.w}, b[4] = {bv.x, bv.y, bv.z, bv.w};
#pragma unroll
      for (int i = 0; i < 4; i++)
#pragma unroll
        for (int j = 0; j < 4; j++) acc[i][j] = fmaf(a[i], b[j], acc[i][j]);
    }
    __syncthreads();
  }
#pragma unroll
  for (int i = 0; i < 4; i++){
    int m = m0 + (ty << 2) + i;
    if (m >= p.M) continue;
#pragma unroll
    for (int j = 0; j < 4; j++){
      int n = n0 + (tx << 2) + j;
      if (n >= p.N) continue;
      float a = acc[i][j];
      if constexpr (MODE == 0){                 // v = hN @ G
        p.C[(size_t)m * p.N + n] = a;
      } else {                                   // MODE 4: h_noise sample (u8)
        size_t fl = (size_t)m * E_ + n;
        float pr = sigf(a + p.bias[n]);
        float u = u01(tf_fold(p.k0, p.k1, (uint32_t)fl));
        ((unsigned char*)p.C)[fl] = (u < pr) ? 1 : 0;
      }
    }
  }
}

// ---------------- phase-2 small kernels ----------------
__global__ __launch_bounds__(256) void k_znoise(const float* __restrict__ nz,
    const float* __restrict__ blp, unsigned char* __restrict__ zn,
    float* __restrict__ lpint, uint32_t k0, uint32_t k1){
  int blk = blockIdx.x;            // n*B + b
  int b = blk & (B_ - 1);
  int t = threadIdx.x;
  float s = 0.f;
  for (int z = t; z < Z_; z += 256){
    float pz = nz[(size_t)b * Z_ + z];
    uint32_t i = (uint32_t)blk * (uint32_t)Z_ + (uint32_t)z;
    float u = u01(tf_fold(k0, k1, i));
    float zv = (u < pz) ? 1.f : 0.f;
    zn[(size_t)blk * Z_ + z] = (unsigned char)zv;
    float x = blp[z];
    float sp = fmaxf(x, 0.f) + log1pf(__expf(-fabsf(x)));
    float post = zv * logf(pz) + (1.f - zv) * log1pf(-pz);
    s += zv * x - sp - post;
  }
  __shared__ float red[256];
  red[t] = s; __syncthreads();
  for (int w = 128; w > 0; w >>= 1){ if (t < w) red[t] += red[t + w]; __syncthreads(); }
  if (!t) lpint[blk] = red[0];
}

__global__ __launch_bounds__(256) void k_joint(const unsigned char* __restrict__ hN,
    const float* __restrict__ v, const float* __restrict__ Pp,
    const float* __restrict__ r2, const float* __restrict__ lpint,
    const float* __restrict__ bso, float* __restrict__ joint){
  int m = blockIdx.x, t = threadIdx.x;
  int b = m & (B_ - 1);
  float h = (float)hN[(size_t)m * E_ + t];
  float s1 = h * v[(size_t)m * E_ + t];
  float s2 = h * Pp[(size_t)b * E_ + t];
  __shared__ float rA[256], rB[256];
  rA[t] = s1; rB[t] = s2; __syncthreads();
  for (int w = 128; w > 0; w >>= 1){
    if (t < w){ rA[t] += rA[t + w]; rB[t] += rB[t + w]; }
    __syncthreads();
  }
  if (!t){
    float bs = bso[0];
    float isc2 = __expf(-2.f * bs);
    float se = r2[b] - 2.f * rB[0] + rA[0];
    joint[m] = lpint[m] - 0.5f * isc2 * se - (float)FV_ * (bs + 0.91893853320467274f);
  }
}

__global__ __launch_bounds__(1024) void k_final(const float* __restrict__ joint, float* __restrict__ out){
  int b = threadIdx.x;
  float mx = -3.0e38f;
  for (int n = 0; n < NS_; n++) mx = fmaxf(mx, joint[(size_t)n * B_ + b]);
  float s = 0.f;
  for (int n = 0; n < NS_; n++) s += __expf(joint[(size_t)n * B_ + b] - mx);
  float lse = mx + logf(s) - logf((float)NS_);
  __shared__ float red[1024];
  red[b] = lse; __syncthreads();
  for (int w = 512; w > 0; w >>= 1){ if (b < w) red[b] += red[b + w]; __syncthreads(); }
  if (!b) out[0] = -red[0] / (float)B_;
}

// ---------------- host ----------------
extern "C" void kernel_launch(void* const* d_in, const int* in_sizes, int n_in,
                              void* d_out, int out_size, void* d_ws, size_t ws_size,
                              hipStream_t stream){
  const float* img  = (const float*)d_in[0];
  const float* W    = (const float*)d_in[2];
  const float* wb   = (const float*)d_in[3];
  const float* whz  = (const float*)d_in[4];
  const float* whzb = (const float*)d_in[5];
  const float* blp  = (const float*)d_in[6];
  const float* bso  = (const float*)d_in[7];
  float* out = (float*)d_out;
  float* ws = (float*)d_ws;
  (void)in_sizes; (void)n_in; (void)out_size; (void)ws_size;

  size_t off = 0;
  auto nxt = [&](size_t n){ size_t o = off; off += (n + 63) & ~(size_t)63; return o; };
  float* G      = ws + nxt((size_t)E_ * E_);                    // 65536
  float* Pp     = ws + nxt((size_t)B_ * E_);                    // 262144
  float* r2     = ws + nxt(B_);
  float* lpint  = ws + nxt(NSB_);
  float* joint  = ws + nxt(NSB_);
  float* nzF    = ws + nxt((size_t)B_ * Z_);                    // 263168
  unsigned short* whzPh  = (unsigned short*)(ws + nxt((size_t)E_ * 260 / 2 + 32));
  unsigned short* whzTPh = (unsigned short*)(ws + nxt((size_t)Z_ * E_ / 2 + 32));
  unsigned short* Gh     = (unsigned short*)(ws + nxt((size_t)E_ * E_ / 2 + 32));
  float* big0   = ws + nxt((size_t)16 * B_ * E_);               // ppPart, later v (both 4194304)
  float* znRgn  = ws + nxt(((size_t)NSB_ * Z_ + 3) / 4);        // zn u8, earlier ataPart
  unsigned char* hN = (unsigned char*)(ws + nxt(((size_t)NSB_ * E_ + 3) / 4));

  float* ppPart  = big0;
  float* v       = big0;
  float* ataPart = znRgn;            // 16*65536 floats fits inside zn region
  unsigned char* zn = (unsigned char*)znRgn;

  // phase-2 sampling keys (split of key(7))
  uint32_t sk00, sk01, sk10, sk11;
  tf2x32(0u, 7u, 0u, 0u, &sk00, &sk01);
  tf2x32(0u, 7u, 0u, 1u, &sk10, &sk11);

  // ---- setup ----
  k_prep<<<dim3(Z_), dim3(E_), 0, stream>>>(whz, whzPh, whzTPh);
  k_ata_split<<<dim3(4, 4, 16), 256, 0, stream>>>(W, ataPart);
  k_reduce16<<<dim3(E_ * E_ / 256), 256, 0, stream>>>(ataPart, G, Gh, E_ * E_);
  k_pp_split<<<dim3(4, 16, 16), 256, 0, stream>>>(img, wb, W, ppPart);
  k_reduce16<<<dim3(B_ * E_ / 256), 256, 0, stream>>>(ppPart, Pp, nullptr, B_ * E_);
  k_r2<<<dim3(B_), 256, 0, stream>>>(img, wb, r2);

  // ---- fused inner loop (8 steps) ----
  k_inner<<<dim3(B_ / 4), 512, 0, stream>>>(whzPh, whzTPh, Gh, whzb, blp, Pp, bso, nzF);

  // ---- phase 2 ----
  k_znoise<<<dim3(NSB_), 256, 0, stream>>>(nzF, blp, zn, lpint, sk00, sk01);

  GP p4 = {};
  p4.A = (const float*)zn; p4.Bm = whz; p4.C = (float*)hN;
  p4.M = NSB_; p4.N = E_; p4.K = Z_; p4.lda = Z_; p4.ldb = Z_;
  p4.bias = whzb; p4.k0 = sk10; p4.k1 = sk11;
  gemm_nt<4, true><<<dim3(4, 256), 256, 0, stream>>>(p4);

  GP p0 = {};
  p0.A = (const float*)hN; p0.Bm = G; p0.C = v;
  p0.M = NSB_; p0.N = E_; p0.K = E_; p0.lda = E_; p0.ldb = E_;
  gemm_nt<0, true><<<dim3(4, 256), 256, 0, stream>>>(p0);

  k_joint<<<dim3(NSB_), 256, 0, stream>>>(hN, v, Pp, r2, lpint, bso, joint);
  k_final<<<dim3(1), 1024, 0, stream>>>(joint, out);
}

// Round 3
// 253.940 us; speedup vs baseline: 7.0069x; 1.9950x over previous
//
#include <hip/hip_runtime.h>
#include <stdint.h>

#define B_    1024
#define FV_   4096
#define E_    256
#define Z_    257
#define NS_   16
#define NSB_  16384
#define EPS_  1e-3f

typedef __attribute__((ext_vector_type(8))) short short8v;
typedef __attribute__((ext_vector_type(4))) float f32x4;
#define MFMA16(a,b,c) __builtin_amdgcn_mfma_f32_16x16x32_bf16(a,b,c,0,0,0)

// ---------------- threefry2x32 (20 rounds) ----------------
__host__ __device__ __forceinline__ uint32_t rotl32(uint32_t v, int r){
  return (v << r) | (v >> (32 - r));
}
__host__ __device__ __forceinline__ void tf2x32(uint32_t k0, uint32_t k1,
    uint32_t x0, uint32_t x1, uint32_t* o0, uint32_t* o1){
  uint32_t ks2 = k0 ^ k1 ^ 0x1BD11BDAu;
  x0 += k0; x1 += k1;
#define TFR(r) { x0 += x1; x1 = rotl32(x1, (r)); x1 ^= x0; }
  TFR(13) TFR(15) TFR(26) TFR(6)
  x0 += k1;  x1 += ks2 + 1u;
  TFR(17) TFR(29) TFR(16) TFR(24)
  x0 += ks2; x1 += k0 + 2u;
  TFR(13) TFR(15) TFR(26) TFR(6)
  x0 += k0;  x1 += k1 + 3u;
  TFR(17) TFR(29) TFR(16) TFR(24)
  x0 += k1;  x1 += ks2 + 4u;
  TFR(13) TFR(15) TFR(26) TFR(6)
  x0 += ks2; x1 += k0 + 5u;
#undef TFR
  *o0 = x0; *o1 = x1;
}
__device__ __forceinline__ uint64_t tf64(uint32_t k0, uint32_t k1, uint32_t c){
  uint32_t a, b; tf2x32(k0, k1, 0u, c, &a, &b);
  return ((uint64_t)b << 32) | (uint64_t)a;
}
__device__ __forceinline__ float u01(uint32_t bits){
  return __uint_as_float((bits >> 9) | 0x3f800000u) - 1.0f;
}
__device__ __forceinline__ float logsigf(float x){
  return fminf(x, 0.f) - __logf(1.f + __expf(-fabsf(x)));
}
__device__ __forceinline__ float sigf(float x){ return 1.f / (1.f + __expf(-x)); }
__device__ __forceinline__ unsigned short f2bf(float f){
  uint32_t b = __float_as_uint(f);
  return (unsigned short)((b + 0x7fffu + ((b >> 16) & 1u)) >> 16);
}
__device__ __forceinline__ float bf2f(unsigned short u){
  return __uint_as_float(((uint32_t)u) << 16);
}

// ---------------- prep kernels ----------------
// whzPh [256][288] bf16 (rows of whz, zero-padded cols>=257)
// whzTPh [272][256] bf16 (transpose, rows>=257 zero)
__global__ void k_prepw(const float* __restrict__ whz,
                        unsigned short* __restrict__ whzPh,
                        unsigned short* __restrict__ whzTPh){
  int r = blockIdx.x, t = threadIdx.x;    // grid 272 x 256
  if (r < 256){
    for (int z = t; z < 288; z += 256)
      whzPh[(size_t)r * 288 + z] = (z < Z_) ? f2bf(whz[(size_t)r * Z_ + z]) : (unsigned short)0;
  }
  whzTPh[(size_t)r * 256 + t] = (r < Z_) ? f2bf(whz[(size_t)t * Z_ + r]) : (unsigned short)0;
}

// imgb = bf16(img - wb)  [1024][4096]
__global__ void k_prepimg(const float* __restrict__ img, const float* __restrict__ wb,
                          unsigned short* __restrict__ imgb){
  int i = (blockIdx.x * 256 + threadIdx.x) * 4;   // grid 4096
  float4 v = *(const float4*)&img[i];
  int f = i & (FV_ - 1);
  ushort4 o;
  o.x = f2bf(v.x - wb[f]);
  o.y = f2bf(v.y - wb[f + 1]);
  o.z = f2bf(v.z - wb[f + 2]);
  o.w = f2bf(v.w - wb[f + 3]);
  *(ushort4*)&imgb[i] = o;
}

// Wt bf16 [256][4096] = W^T
__global__ void k_prepwt(const float* __restrict__ W, unsigned short* __restrict__ Wt){
  __shared__ float ld[32][33];
  int f0 = blockIdx.x * 32, e0 = blockIdx.y * 32;   // grid (128, 8)
  int t = threadIdx.x, tx = t & 31, ty = t >> 5;
#pragma unroll
  for (int sub = 0; sub < 4; sub++){
    int r = ty + 8 * sub;
    ld[r][tx] = W[(size_t)(f0 + r) * 256 + e0 + tx];
  }
  __syncthreads();
#pragma unroll
  for (int sub = 0; sub < 4; sub++){
    int r = ty + 8 * sub;
    Wt[(size_t)(e0 + r) * 4096 + f0 + tx] = f2bf(ld[tx][r]);
  }
}

__global__ void k_r2(const float* __restrict__ img, const float* __restrict__ wb,
                     float* __restrict__ r2){
  int b = blockIdx.x, t = threadIdx.x;
  float s = 0.f;
  for (int f = t; f < FV_; f += 256){
    float v = img[(size_t)b * FV_ + f] - wb[f];
    s = fmaf(v, v, s);
  }
  __shared__ float red[256];
  red[t] = s; __syncthreads();
  for (int w = 128; w > 0; w >>= 1){ if (t < w) red[t] += red[t + w]; __syncthreads(); }
  if (!t) r2[b] = red[0];
}

// G = Wt @ Wt^T (bf16 MFMA, splitK): grid (4, 16)
__global__ __launch_bounds__(256) void k_ata_mfma(const unsigned short* __restrict__ Wt,
                                                  float* __restrict__ part){
  int t = threadIdx.x, lane = t & 63, w = t >> 6, l15 = lane & 15, l4 = lane >> 4;
  int m0 = blockIdx.x * 64 + w * 16;
  size_t kc = (size_t)blockIdx.y * 256;
  short8v af[8];
#pragma unroll
  for (int kt = 0; kt < 8; kt++)
    af[kt] = *(const short8v*)&Wt[(size_t)(m0 + l15) * 4096 + kc + kt * 32 + l4 * 8];
  float* dst = part + (size_t)blockIdx.y * 65536;
  for (int nt = 0; nt < 16; nt++){
    f32x4 acc = {0.f, 0.f, 0.f, 0.f};
#pragma unroll
    for (int kt = 0; kt < 8; kt++){
      short8v bf_ = *(const short8v*)&Wt[(size_t)(nt * 16 + l15) * 4096 + kc + kt * 32 + l4 * 8];
      acc = MFMA16(af[kt], bf_, acc);
    }
#pragma unroll
    for (int j = 0; j < 4; j++)
      dst[(size_t)(m0 + l4 * 4 + j) * 256 + nt * 16 + l15] = acc[j];
  }
}

// Pp partial = imgb @ Wt^T (splitK): grid (16, 4)
__global__ __launch_bounds__(256) void k_pp_mfma(const unsigned short* __restrict__ imgb,
                                                 const unsigned short* __restrict__ Wt,
                                                 float* __restrict__ part){
  int t = threadIdx.x, lane = t & 63, w = t >> 6, l15 = lane & 15, l4 = lane >> 4;
  int m0 = blockIdx.x * 64 + w * 16;
  size_t kc = (size_t)blockIdx.y * 1024;
  f32x4 acc[16];
#pragma unroll
  for (int nt = 0; nt < 16; nt++) acc[nt] = (f32x4){0.f, 0.f, 0.f, 0.f};
  for (int kt = 0; kt < 32; kt++){
    short8v a = *(const short8v*)&imgb[(size_t)(m0 + l15) * 4096 + kc + kt * 32 + l4 * 8];
#pragma unroll
    for (int nt = 0; nt < 16; nt++){
      short8v b = *(const short8v*)&Wt[(size_t)(nt * 16 + l15) * 4096 + kc + kt * 32 + l4 * 8];
      acc[nt] = MFMA16(a, b, acc[nt]);
    }
  }
  float* dst = part + (size_t)blockIdx.y * (B_ * 256);
#pragma unroll
  for (int nt = 0; nt < 16; nt++)
#pragma unroll
    for (int j = 0; j < 4; j++)
      dst[(size_t)(m0 + l4 * 4 + j) * 256 + nt * 16 + l15] = acc[nt][j];
}

template<int P, bool BF>
__global__ void k_reduceP(const float* __restrict__ src, float* __restrict__ dstF,
                          unsigned short* __restrict__ dstH, int n){
  int i = blockIdx.x * 256 + threadIdx.x;
  if (i >= n) return;
  float s = 0.f;
#pragma unroll
  for (int p = 0; p < P; p++) s += src[(size_t)p * n + i];
  if (BF) dstH[i] = f2bf(s); else dstF[i] = s;
}

// ---------------- fused 8-step inner loop (MFMA) ----------------
// 64 blocks x 256 threads (4 waves); 16 rows/block; state in LDS.
__global__ __launch_bounds__(256) void k_inner(
    const unsigned short* __restrict__ whzPh,   // [256][288]
    const unsigned short* __restrict__ whzTPh,  // [272][256]
    const unsigned short* __restrict__ Gh,      // [256][256]
    const float* __restrict__ whzb,
    const float* __restrict__ blp,
    const float* __restrict__ Pp,
    const float* __restrict__ bso,
    float* __restrict__ nzOut,                  // [B][257]
    uint32_t hk00, uint32_t hk01, uint32_t hk10, uint32_t hk11,
    uint32_t zk00, uint32_t zk01, uint32_t zk10, uint32_t zk11)
{
  __shared__ float zl[16][260];
  __shared__ float hl[16][260];
  __shared__ unsigned short zb[16][296];
  __shared__ unsigned short hb[16][264];
  __shared__ unsigned short sgb[16][264];
  __shared__ float lsb[272];

  const int t = threadIdx.x;
  const int lane = t & 63;
  const int w = t >> 6;
  const int l15 = lane & 15;
  const int l4 = lane >> 4;
  const int blk = blockIdx.x;
  const int b0 = blk * 16;

  for (int i = t; i < 16 * 260; i += 256){
    int r = i / 260, c = i % 260;
    zl[r][c] = (c < Z_) ? EPS_ : 0.f;
    hl[r][c] = (c < 256) ? EPS_ : 0.f;
  }
  const unsigned short epsb = f2bf(EPS_);
  for (int i = t; i < 16 * 296; i += 256){
    int r = i / 296, c = i % 296;
    zb[r][c] = (c < Z_) ? epsb : (unsigned short)0;
  }
  for (int i = t; i < 16 * 264; i += 256){
    int r = i / 264, c = i % 264;
    hb[r][c] = (c < 256) ? epsb : (unsigned short)0;
  }
  for (int i = t; i < 272; i += 256) lsb[i] = (i < Z_) ? logsigf(blp[i]) : 0.f;
  __syncthreads();

  const float op = __expf(2.f * bso[0]);
  float wbr[4], ppr[4][4], lsr[5];
  uint64_t hbits[4][2], zbits[5][2];
#pragma unroll
  for (int nt = 0; nt < 4; nt++){
    int n = w * 64 + nt * 16 + l15;
    wbr[nt] = whzb[n];
    lsr[nt] = lsb[n];
#pragma unroll
    for (int j = 0; j < 4; j++)
      ppr[nt][j] = Pp[(size_t)(b0 + l4 * 4 + j) * 256 + n];
    hbits[nt][0] = tf64(hk00, hk01, (uint32_t)(blk * 272 + n));
    hbits[nt][1] = tf64(hk10, hk11, (uint32_t)(blk * 272 + n));
    zbits[nt][0] = tf64(zk00, zk01, (uint32_t)(blk * 272 + n));
    zbits[nt][1] = tf64(zk10, zk11, (uint32_t)(blk * 272 + n));
  }
  {
    int n = 256 + l15;
    lsr[4] = lsb[n];
    zbits[4][0] = tf64(zk00, zk01, (uint32_t)(blk * 272 + n));
    zbits[4][1] = tf64(zk10, zk11, (uint32_t)(blk * 272 + n));
  }

  for (int s = 0; s < 8; s++){
    const int sg = s >> 2, sh = (s & 3) << 4;
    // ---- phase A: hpl = z @ whz^T + b ----
    short8v za[9];
#pragma unroll
    for (int kt = 0; kt < 9; kt++)
      za[kt] = *(const short8v*)&zb[l15][kt * 32 + l4 * 8];
    f32x4 accA[4];
#pragma unroll
    for (int nt = 0; nt < 4; nt++) accA[nt] = (f32x4){0.f, 0.f, 0.f, 0.f};
#pragma unroll
    for (int kt = 0; kt < 9; kt++){
#pragma unroll
      for (int nt = 0; nt < 4; nt++){
        int n = w * 64 + nt * 16 + l15;
        short8v bfr = *(const short8v*)&whzPh[(size_t)n * 288 + kt * 32 + l4 * 8];
        accA[nt] = MFMA16(za[kt], bfr, accA[nt]);
      }
    }
    float d2r[4][4];
#pragma unroll
    for (int nt = 0; nt < 4; nt++){
      int n = w * 64 + nt * 16 + l15;
#pragma unroll
      for (int j = 0; j < 4; j++){
        int m = l4 * 4 + j;
        float hpl = accA[nt][j] + wbr[nt];
        d2r[nt][j] = logsigf(hpl);
        float sv = hl[m][n] * (1.f / (1.f + __expf(hpl)));
        sgb[m][n] = f2bf(sv);
      }
    }
    __syncthreads();   // S1: sgb complete

    // ---- phase B: gh = h @ G; h update ----
    short8v ha[8];
#pragma unroll
    for (int kt = 0; kt < 8; kt++)
      ha[kt] = *(const short8v*)&hb[l15][kt * 32 + l4 * 8];
    f32x4 accB[4];
#pragma unroll
    for (int nt = 0; nt < 4; nt++) accB[nt] = (f32x4){0.f, 0.f, 0.f, 0.f};
#pragma unroll
    for (int kt = 0; kt < 8; kt++){
#pragma unroll
      for (int nt = 0; nt < 4; nt++){
        int n = w * 64 + nt * 16 + l15;
        short8v bfr = *(const short8v*)&Gh[(size_t)n * 256 + kt * 32 + l4 * 8];
        accB[nt] = MFMA16(ha[kt], bfr, accB[nt]);
      }
    }
    float newh[4][4];
#pragma unroll
    for (int nt = 0; nt < 4; nt++){
      int n = w * 64 + nt * 16 + l15;
#pragma unroll
      for (int j = 0; j < 4; j++){
        int m = l4 * 4 + j;
        float hn = sigf(op * (ppr[nt][j] - accB[nt][j]) + d2r[nt][j]);
        float old = hl[m][n];
        int bit = (int)((hbits[nt][sg] >> (sh | m)) & 1ull);
        newh[nt][j] = bit ? 0.5f * (old + hn) : old;
      }
    }
    __syncthreads();   // S2: all hb/hl reads done
#pragma unroll
    for (int nt = 0; nt < 4; nt++){
      int n = w * 64 + nt * 16 + l15;
#pragma unroll
      for (int j = 0; j < 4; j++){
        int m = l4 * 4 + j;
        hl[m][n] = newh[nt][j];
        hb[m][n] = f2bf(newh[nt][j]);
      }
    }

    // ---- phase C: dz = sg @ whz; z update ----
    short8v sa[8];
#pragma unroll
    for (int kt = 0; kt < 8; kt++)
      sa[kt] = *(const short8v*)&sgb[l15][kt * 32 + l4 * 8];
    f32x4 accC[5];
#pragma unroll
    for (int nt = 0; nt < 5; nt++) accC[nt] = (f32x4){0.f, 0.f, 0.f, 0.f};
#pragma unroll
    for (int kt = 0; kt < 8; kt++){
#pragma unroll
      for (int nt = 0; nt < 5; nt++){
        if (nt < 4 || w == 0){
          int n0 = (nt < 4) ? (w * 64 + nt * 16) : 256;
          short8v bfr = *(const short8v*)&whzTPh[(size_t)(n0 + l15) * 256 + kt * 32 + l4 * 8];
          accC[nt] = MFMA16(sa[kt], bfr, accC[nt]);
        }
      }
    }
#pragma unroll
    for (int nt = 0; nt < 5; nt++){
      if (nt < 4 || w == 0){
        int n = ((nt < 4) ? (w * 64 + nt * 16) : 256) + l15;
        if (n < Z_){
#pragma unroll
          for (int j = 0; j < 4; j++){
            int m = l4 * 4 + j;
            float zx = sigf(accC[nt][j] + lsr[nt]);
            float old = zl[m][n];
            int bit = (int)((zbits[nt][sg] >> (sh | m)) & 1ull);
            float nz = bit ? 0.5f * (old + zx) : old;
            zl[m][n] = nz;
            zb[m][n] = f2bf(nz);
          }
        }
      }
    }
    __syncthreads();   // S3: zb/hb visible for next step
  }

  for (int i = t; i < 16 * Z_; i += 256){
    int r = i / Z_, c = i % Z_;
    nzOut[(size_t)(b0 + r) * Z_ + c] = zl[r][c];
  }
}

// ---------------- phase-2 kernels ----------------
// cA[b][z], rowB[b]
__global__ __launch_bounds__(256) void k_zprep(const float* __restrict__ nzF,
    const float* __restrict__ blp, float* __restrict__ cA, float* __restrict__ rowB){
  int b = blockIdx.x, t = threadIdx.x;
  float s = 0.f;
  for (int z = t; z < Z_; z += 256){
    float pz = nzF[(size_t)b * Z_ + z];
    float lgp = __logf(pz);
    float lgq = log1pf(-pz);
    float x = blp[z];
    float sp = fmaxf(x, 0.f) + __logf(1.f + __expf(-fabsf(x)));
    cA[(size_t)b * Z_ + z] = x - lgp + lgq;
    s += -sp - lgq;
  }
  __shared__ float red[256];
  red[t] = s; __syncthreads();
  for (int w = 128; w > 0; w >>= 1){ if (t < w) red[t] += red[t + w]; __syncthreads(); }
  if (!t) rowB[b] = red[0];
}

// sample z_noise (bf16 into znb [16384][288]) + lpint
__global__ __launch_bounds__(128) void k_znoise(const float* __restrict__ nzF,
    const float* __restrict__ cA, const float* __restrict__ rowB,
    unsigned short* __restrict__ znb, float* __restrict__ lpint,
    uint32_t k0, uint32_t k1){
  int r = blockIdx.x, t = threadIdx.x;   // 16384 x 128
  int b = r & (B_ - 1);
  float acc = 0.f;
  uint32_t o0, o1;
  tf2x32(k0, k1, 0u, (uint32_t)(r * 130 + t), &o0, &o1);
  int z0 = 2 * t, z1 = 2 * t + 1;
  {
    float pz = nzF[(size_t)b * Z_ + z0];
    int zv = u01(o0) < pz;
    znb[(size_t)r * 288 + z0] = zv ? (unsigned short)0x3F80 : (unsigned short)0;
    if (zv) acc += cA[(size_t)b * Z_ + z0];
  }
  {
    float pz = nzF[(size_t)b * Z_ + z1];
    int zv = u01(o1) < pz;
    znb[(size_t)r * 288 + z1] = zv ? (unsigned short)0x3F80 : (unsigned short)0;
    if (zv) acc += cA[(size_t)b * Z_ + z1];
  }
  if (t == 0){
    uint32_t p0, p1;
    tf2x32(k0, k1, 0u, (uint32_t)(r * 130 + 128), &p0, &p1);
    float pz = nzF[(size_t)b * Z_ + 256];
    int zv = u01(p0) < pz;
    znb[(size_t)r * 288 + 256] = zv ? (unsigned short)0x3F80 : (unsigned short)0;
    if (zv) acc += cA[(size_t)b * Z_ + 256];
  }
  if (t < 31) znb[(size_t)r * 288 + 257 + t] = 0;
  __shared__ float red[128];
  red[t] = acc; __syncthreads();
  for (int w = 64; w > 0; w >>= 1){ if (t < w) red[t] += red[t + w]; __syncthreads(); }
  if (!t) lpint[r] = rowB[b] + red[0];
}

// h_post = zn @ whz^T + b ; sample h -> hnb bf16 [16384][256]
__global__ __launch_bounds__(256) void k_gemm1(const unsigned short* __restrict__ znb,
    const unsigned short* __restrict__ whzPh, const float* __restrict__ whzb,
    unsigned short* __restrict__ hnb, uint32_t k0, uint32_t k1){
  int t = threadIdx.x, lane = t & 63, w = t >> 6, l15 = lane & 15, l4 = lane >> 4;
  int m0 = blockIdx.x * 64 + w * 16;    // grid 256
  short8v af[9];
#pragma unroll
  for (int kt = 0; kt < 9; kt++)
    af[kt] = *(const short8v*)&znb[(size_t)(m0 + l15) * 288 + kt * 32 + l4 * 8];
  for (int nt = 0; nt < 16; nt++){
    f32x4 acc = {0.f, 0.f, 0.f, 0.f};
#pragma unroll
    for (int kt = 0; kt < 9; kt++){
      short8v b = *(const short8v*)&whzPh[(size_t)(nt * 16 + l15) * 288 + kt * 32 + l4 * 8];
      acc = MFMA16(af[kt], b, acc);
    }
    int n = nt * 16 + l15;
    float wbv = whzb[n];
    uint32_t c0 = (uint32_t)(((m0 + l4 * 4) >> 1) * 256 + n);
    uint32_t a0, b0, a1, b1;
    tf2x32(k0, k1, 0u, c0, &a0, &b0);
    tf2x32(k0, k1, 0u, c0 + 256, &a1, &b1);
    float u[4] = {u01(a0), u01(b0), u01(a1), u01(b1)};
#pragma unroll
    for (int j = 0; j < 4; j++){
      float pr = sigf(acc[j] + wbv);
      hnb[(size_t)(m0 + l4 * 4 + j) * 256 + n] = (u[j] < pr) ? (unsigned short)0x3F80 : (unsigned short)0;
    }
  }
}

// v = h @ G fused with s1/s2 reduction and joint epilogue
__global__ __launch_bounds__(256) void k_gemm2(const unsigned short* __restrict__ hnb,
    const unsigned short* __restrict__ Gh, const float* __restrict__ Pp,
    const float* __restrict__ r2, const float* __restrict__ lpint,
    const float* __restrict__ bso, float* __restrict__ joint){
  int t = threadIdx.x, lane = t & 63, w = t >> 6, l15 = lane & 15, l4 = lane >> 4;
  int m0 = blockIdx.x * 64 + w * 16;    // grid 256
  short8v af[8];
#pragma unroll
  for (int kt = 0; kt < 8; kt++)
    af[kt] = *(const short8v*)&hnb[(size_t)(m0 + l15) * 256 + kt * 32 + l4 * 8];
  float s1[4] = {0.f, 0.f, 0.f, 0.f}, s2[4] = {0.f, 0.f, 0.f, 0.f};
  for (int nt = 0; nt < 16; nt++){
    f32x4 acc = {0.f, 0.f, 0.f, 0.f};
#pragma unroll
    for (int kt = 0; kt < 8; kt++){
      short8v b = *(const short8v*)&Gh[(size_t)(nt * 16 + l15) * 256 + kt * 32 + l4 * 8];
      acc = MFMA16(af[kt], b, acc);
    }
    int n = nt * 16 + l15;
#pragma unroll
    for (int j = 0; j < 4; j++){
      int gm = m0 + l4 * 4 + j;
      float hv = bf2f(hnb[(size_t)gm * 256 + n]);
      float ppv = Pp[(size_t)(gm & (B_ - 1)) * 256 + n];
      s1[j] = fmaf(hv, acc[j], s1[j]);
      s2[j] = fmaf(hv, ppv, s2[j]);
    }
  }
#pragma unroll
  for (int j = 0; j < 4; j++){
#pragma unroll
    for (int msk = 1; msk < 16; msk <<= 1){
      s1[j] += __shfl_xor(s1[j], msk);
      s2[j] += __shfl_xor(s2[j], msk);
    }
  }
  if (l15 == 0){
    float bs = bso[0];
    float isc2 = __expf(-2.f * bs);
#pragma unroll
    for (int j = 0; j < 4; j++){
      int gm = m0 + l4 * 4 + j;
      int b = gm & (B_ - 1);
      float se = r2[b] - 2.f * s2[j] + s1[j];
      joint[gm] = lpint[gm] - 0.5f * isc2 * se - (float)FV_ * (bs + 0.91893853320467274f);
    }
  }
}

__global__ __launch_bounds__(1024) void k_final(const float* __restrict__ joint, float* __restrict__ out){
  int b = threadIdx.x;
  float mx = -3.0e38f;
  for (int n = 0; n < NS_; n++) mx = fmaxf(mx, joint[(size_t)n * B_ + b]);
  float s = 0.f;
  for (int n = 0; n < NS_; n++) s += __expf(joint[(size_t)n * B_ + b] - mx);
  float lse = mx + __logf(s) - 2.772588722239781f;   // log(16)
  __shared__ float red[1024];
  red[b] = lse; __syncthreads();
  for (int w = 512; w > 0; w >>= 1){ if (b < w) red[b] += red[b + w]; __syncthreads(); }
  if (!b) out[0] = -red[0] / (float)B_;
}

// ---------------- host ----------------
extern "C" void kernel_launch(void* const* d_in, const int* in_sizes, int n_in,
                              void* d_out, int out_size, void* d_ws, size_t ws_size,
                              hipStream_t stream){
  const float* img  = (const float*)d_in[0];
  const float* W    = (const float*)d_in[2];
  const float* wb   = (const float*)d_in[3];
  const float* whz  = (const float*)d_in[4];
  const float* whzb = (const float*)d_in[5];
  const float* blp  = (const float*)d_in[6];
  const float* bso  = (const float*)d_in[7];
  float* out = (float*)d_out;
  float* ws = (float*)d_ws;
  (void)in_sizes; (void)n_in; (void)out_size; (void)ws_size;

  size_t off = 0;
  auto nxt = [&](size_t n){ size_t o = off; off += (n + 63) & ~(size_t)63; return o; };
  float* Pp    = ws + nxt((size_t)B_ * 256);
  float* r2    = ws + nxt(B_);
  float* lpint = ws + nxt(NSB_);
  float* joint = ws + nxt(NSB_);
  float* nzF   = ws + nxt((size_t)B_ * Z_);
  float* cA    = ws + nxt((size_t)B_ * Z_);
  float* rowB  = ws + nxt(B_);
  unsigned short* Gh     = (unsigned short*)(ws + nxt((size_t)256 * 256 / 2));
  unsigned short* whzPh  = (unsigned short*)(ws + nxt((size_t)256 * 288 / 2));
  unsigned short* whzTPh = (unsigned short*)(ws + nxt((size_t)272 * 256 / 2));
  unsigned short* Wt     = (unsigned short*)(ws + nxt((size_t)256 * 4096 / 2));
  unsigned short* imgb   = (unsigned short*)(ws + nxt((size_t)B_ * FV_ / 2));
  float* znRgn = ws + nxt((size_t)NSB_ * 288 / 2);     // znb bf16; earlier ataPart f32
  float* hnRgn = ws + nxt((size_t)NSB_ * 256 / 2);     // hnb bf16; earlier ppPart f32

  unsigned short* znb = (unsigned short*)znRgn;
  unsigned short* hnb = (unsigned short*)hnRgn;
  float* ataPart = znRgn;    // 16*65536 = 1,048,576 f <= 2,359,296 f  ✓
  float* ppPart  = hnRgn;    // 4*262144 = 1,048,576 f <= 2,097,152 f  ✓

  // host-side key derivation
  uint32_t hk00, hk01, hk10, hk11, zk00, zk01, zk10, zk11;
  tf2x32(0u, 42u, 1u, 0u, &hk00, &hk01);
  tf2x32(0u, 42u, 1u, 1u, &hk10, &hk11);
  tf2x32(0u, 42u, 2u, 0u, &zk00, &zk01);
  tf2x32(0u, 42u, 2u, 1u, &zk10, &zk11);
  uint32_t sk00, sk01, sk10, sk11;
  tf2x32(0u, 7u, 0u, 0u, &sk00, &sk01);
  tf2x32(0u, 7u, 0u, 1u, &sk10, &sk11);

  // ---- setup ----
  k_prepw<<<dim3(272), 256, 0, stream>>>(whz, whzPh, whzTPh);
  k_prepimg<<<dim3(4096), 256, 0, stream>>>(img, wb, imgb);
  k_prepwt<<<dim3(128, 8), 256, 0, stream>>>(W, Wt);
  k_r2<<<dim3(B_), 256, 0, stream>>>(img, wb, r2);
  k_ata_mfma<<<dim3(4, 16), 256, 0, stream>>>(Wt, ataPart);
  k_reduceP<16, true><<<dim3(256), 256, 0, stream>>>(ataPart, nullptr, Gh, 65536);
  k_pp_mfma<<<dim3(16, 4), 256, 0, stream>>>(imgb, Wt, ppPart);
  k_reduceP<4, false><<<dim3(1024), 256, 0, stream>>>(ppPart, Pp, nullptr, B_ * 256);

  // ---- inner loop ----
  k_inner<<<dim3(64), 256, 0, stream>>>(whzPh, whzTPh, Gh, whzb, blp, Pp, bso, nzF,
                                        hk00, hk01, hk10, hk11, zk00, zk01, zk10, zk11);

  // ---- phase 2 ----
  k_zprep<<<dim3(B_), 256, 0, stream>>>(nzF, blp, cA, rowB);
  k_znoise<<<dim3(NSB_), 128, 0, stream>>>(nzF, cA, rowB, znb, lpint, sk00, sk01);
  k_gemm1<<<dim3(256), 256, 0, stream>>>(znb, whzPh, whzb, hnb, sk10, sk11);
  k_gemm2<<<dim3(256), 256, 0, stream>>>(hnb, Gh, Pp, r2, lpint, bso, joint);
  k_final<<<dim3(1), 1024, 0, stream>>>(joint, out);
}